// Round 1
// baseline (775.678 us; speedup 1.0000x reference)
//
#include <hip/hip_runtime.h>
#include <math.h>

#define SEQ   2048
#define BATCH 2
#define NHEAD 8
#define DHEAD 64
#define HID   512

// ---------------- GEMM: C[M,512] = A[M,512] @ W[512,512] + bias ----------------
// 64x64 block tile, BK=16, 256 threads, 4x4 per thread (outer product).
__global__ __launch_bounds__(256) void gemm_bias_kernel(
    const float* __restrict__ A, const float* __restrict__ W,
    const float* __restrict__ bias, float* __restrict__ C, int M)
{
    __shared__ float As[16][68];   // [k][m], stride 68 -> 2-way-max bank aliasing
    __shared__ float Bs[16][64];   // [k][n]
    const int tid = threadIdx.x;
    const int ty = tid >> 4, tx = tid & 15;
    const int row0 = blockIdx.x << 6;
    const int col0 = blockIdx.y << 6;
    const int am = tid >> 2, ak = (tid & 3) << 2;
    const int wk = tid >> 4, wn = (tid & 15) << 2;

    float acc[4][4] = {};
    for (int k0 = 0; k0 < HID; k0 += 16) {
        float4 a4 = *(const float4*)&A[(size_t)(row0 + am) * HID + k0 + ak];
        float4 w4 = *(const float4*)&W[(size_t)(k0 + wk) * HID + col0 + wn];
        __syncthreads();
        As[ak + 0][am] = a4.x; As[ak + 1][am] = a4.y;
        As[ak + 2][am] = a4.z; As[ak + 3][am] = a4.w;
        *(float4*)&Bs[wk][wn] = w4;
        __syncthreads();
        #pragma unroll
        for (int kk = 0; kk < 16; ++kk) {
            float4 a = *(const float4*)&As[kk][ty << 2];
            float4 w = *(const float4*)&Bs[kk][tx << 2];
            acc[0][0] += a.x * w.x; acc[0][1] += a.x * w.y; acc[0][2] += a.x * w.z; acc[0][3] += a.x * w.w;
            acc[1][0] += a.y * w.x; acc[1][1] += a.y * w.y; acc[1][2] += a.y * w.z; acc[1][3] += a.y * w.w;
            acc[2][0] += a.z * w.x; acc[2][1] += a.z * w.y; acc[2][2] += a.z * w.z; acc[2][3] += a.z * w.w;
            acc[3][0] += a.w * w.x; acc[3][1] += a.w * w.y; acc[3][2] += a.w * w.z; acc[3][3] += a.w * w.w;
        }
    }
    float4 bv = *(const float4*)&bias[col0 + (tx << 2)];
    #pragma unroll
    for (int i = 0; i < 4; ++i) {
        float4 o = { acc[i][0] + bv.x, acc[i][1] + bv.y, acc[i][2] + bv.z, acc[i][3] + bv.w };
        *(float4*)&C[(size_t)(row0 + (ty << 2) + i) * HID + col0 + (tx << 2)] = o;
    }
}

// ---------------- rel dots: dqk[b,h,i,r] = sum_d (q+k)[b,i,h,d] * rel_table[r,d] ----------------
// one wave per (b,i,h); 4 waves per block.
__global__ __launch_bounds__(256) void rel_dots_kernel(
    const float* __restrict__ q, const float* __restrict__ k,
    const float* __restrict__ rel_table, float* __restrict__ dqk)
{
    const int w = blockIdx.x * 4 + (threadIdx.x >> 6);
    const int lane = threadIdx.x & 63;
    const int h = w % NHEAD;
    const int is = w / NHEAD;            // b*SEQ + i
    const int b = is / SEQ;
    const int i = is % SEQ;
    const size_t base = (size_t)is * HID + h * 64 + lane;
    const float s = q[base] + k[base];
    float p0 = s * rel_table[lane];
    float p1 = s * rel_table[64 + lane];
    float p2 = s * rel_table[128 + lane];
    #pragma unroll
    for (int off = 32; off; off >>= 1) {
        p0 += __shfl_xor(p0, off);
        p1 += __shfl_xor(p1, off);
        p2 += __shfl_xor(p2, off);
    }
    if (lane == 0) {
        size_t o = (((size_t)b * NHEAD + h) * SEQ + i) << 2;
        dqk[o + 0] = p0; dqk[o + 1] = p1; dqk[o + 2] = p2;
    }
}

// ---------------- pass 1: logits = (q.k^T + dqk[pos])/8, mask; write raw logits; row stats ----------------
// block = (b, h, 64-row tile); streams 64-wide j tiles; 4x4 per thread outer product over d.
__global__ __launch_bounds__(256) void attn_logits_kernel(
    const float* __restrict__ q, const float* __restrict__ k,
    const float* __restrict__ dqk, const int* __restrict__ pos,
    const unsigned char* __restrict__ mask,
    float* __restrict__ logits, float* __restrict__ stats)
{
    __shared__ float QtT[64][68];   // [d][i]
    __shared__ float KtT[64][68];   // [d][j]
    __shared__ float Ds[64][4];     // [i][r]
    const int tid = threadIdx.x;
    const int b = blockIdx.z, h = blockIdx.y;
    const int i0 = blockIdx.x << 6;
    const int ty = tid >> 4, tx = tid & 15;
    const size_t browbase = ((size_t)b * NHEAD + h) * SEQ;

    {   // transposed Q tile load (lane pattern keeps LDS writes 2-way max)
        const int r = tid & 15, c4 = tid >> 4;
        #pragma unroll
        for (int it = 0; it < 4; ++it) {
            const int i = r + (it << 4);
            float4 v4 = *(const float4*)&q[(size_t)(b * SEQ + i0 + i) * HID + h * 64 + (c4 << 2)];
            QtT[(c4 << 2) + 0][i] = v4.x; QtT[(c4 << 2) + 1][i] = v4.y;
            QtT[(c4 << 2) + 2][i] = v4.z; QtT[(c4 << 2) + 3][i] = v4.w;
        }
    }
    Ds[tid >> 2][tid & 3] = dqk[((browbase + i0 + (tid >> 2)) << 2) + (tid & 3)];

    float mrow[4] = { -1e30f, -1e30f, -1e30f, -1e30f };
    float lrow[4] = { 0.f, 0.f, 0.f, 0.f };

    for (int jt = 0; jt < SEQ / 64; ++jt) {
        const int j0 = jt << 6;
        __syncthreads();
        {
            const int r = tid & 15, c4 = tid >> 4;
            #pragma unroll
            for (int it = 0; it < 4; ++it) {
                const int j = r + (it << 4);
                float4 v4 = *(const float4*)&k[(size_t)(b * SEQ + j0 + j) * HID + h * 64 + (c4 << 2)];
                KtT[(c4 << 2) + 0][j] = v4.x; KtT[(c4 << 2) + 1][j] = v4.y;
                KtT[(c4 << 2) + 2][j] = v4.z; KtT[(c4 << 2) + 3][j] = v4.w;
            }
        }
        __syncthreads();

        float acc[4][4] = {};
        #pragma unroll
        for (int d = 0; d < 64; ++d) {
            float4 a  = *(const float4*)&QtT[d][ty << 2];
            float4 kk = *(const float4*)&KtT[d][tx << 2];
            acc[0][0] += a.x * kk.x; acc[0][1] += a.x * kk.y; acc[0][2] += a.x * kk.z; acc[0][3] += a.x * kk.w;
            acc[1][0] += a.y * kk.x; acc[1][1] += a.y * kk.y; acc[1][2] += a.y * kk.z; acc[1][3] += a.y * kk.w;
            acc[2][0] += a.z * kk.x; acc[2][1] += a.z * kk.y; acc[2][2] += a.z * kk.z; acc[2][3] += a.z * kk.w;
            acc[3][0] += a.w * kk.x; acc[3][1] += a.w * kk.y; acc[3][2] += a.w * kk.z; acc[3][3] += a.w * kk.w;
        }

        #pragma unroll
        for (int i = 0; i < 4; ++i) {
            const int ir = (ty << 2) + i;
            const int gi = i0 + ir;
            const int4   p4 = *(const int4*)&pos[(size_t)gi * SEQ + j0 + (tx << 2)];
            const uchar4 mk = *(const uchar4*)&mask[(size_t)b * SEQ * SEQ + (size_t)gi * SEQ + j0 + (tx << 2)];
            float l0 = (acc[i][0] + Ds[ir][p4.x]) * 0.125f;
            float l1 = (acc[i][1] + Ds[ir][p4.y]) * 0.125f;
            float l2 = (acc[i][2] + Ds[ir][p4.z]) * 0.125f;
            float l3 = (acc[i][3] + Ds[ir][p4.w]) * 0.125f;
            if (mk.x) l0 = -1e9f;
            if (mk.y) l1 = -1e9f;
            if (mk.z) l2 = -1e9f;
            if (mk.w) l3 = -1e9f;
            const float mx = fmaxf(fmaxf(l0, l1), fmaxf(l2, l3));
            const float mn = fmaxf(mrow[i], mx);
            lrow[i] = lrow[i] * __expf(mrow[i] - mn)
                    + __expf(l0 - mn) + __expf(l1 - mn) + __expf(l2 - mn) + __expf(l3 - mn);
            mrow[i] = mn;
            float4 o = { l0, l1, l2, l3 };
            *(float4*)&logits[(browbase + gi) * SEQ + j0 + (tx << 2)] = o;
        }
    }

    // merge (m,l) across the 16 lanes sharing each row (lanes differ in tx, same wave)
    #pragma unroll
    for (int i = 0; i < 4; ++i) {
        float m = mrow[i], l = lrow[i];
        #pragma unroll
        for (int off = 1; off < 16; off <<= 1) {
            const float mo = __shfl_xor(m, off);
            const float lo = __shfl_xor(l, off);
            const float mn = fmaxf(m, mo);
            l = l * __expf(m - mn) + lo * __expf(mo - mn);
            m = mn;
        }
        if (tx == 0) {
            const size_t o = (browbase + i0 + (ty << 2) + i) << 1;
            stats[o] = m;
            stats[o + 1] = 1.0f / l;
        }
    }
}

// ---------------- pass 2: normalize attn in place + x = attn @ v ----------------
__global__ __launch_bounds__(256) void attn_pv_kernel(
    float* __restrict__ attn, const float* __restrict__ v,
    const float* __restrict__ stats, float* __restrict__ x)
{
    __shared__ float AtT[64][68];   // [j][i]
    __shared__ float Vt[64][64];    // [j][d]
    __shared__ float Ms[64];
    __shared__ float Li[64];
    const int tid = threadIdx.x;
    const int b = blockIdx.z, h = blockIdx.y;
    const int i0 = blockIdx.x << 6;
    const int ty = tid >> 4, tx = tid & 15;
    const size_t browbase = ((size_t)b * NHEAD + h) * SEQ;

    if (tid < 64) {
        float2 s = *(const float2*)&stats[(browbase + i0 + tid) << 1];
        Ms[tid] = s.x; Li[tid] = s.y;
    }

    float acc[4][4] = {};
    for (int jt = 0; jt < SEQ / 64; ++jt) {
        const int j0 = jt << 6;
        __syncthreads();
        {
            const int r = tid & 15, c4 = tid >> 4;
            #pragma unroll
            for (int it = 0; it < 4; ++it) {
                const int i = r + (it << 4);
                const size_t g = (browbase + i0 + i) * SEQ + j0 + (c4 << 2);
                float4 lv = *(const float4*)&attn[g];
                const float ml = Ms[i], il = Li[i];
                float4 av = { __expf(lv.x - ml) * il, __expf(lv.y - ml) * il,
                              __expf(lv.z - ml) * il, __expf(lv.w - ml) * il };
                *(float4*)&attn[g] = av;
                AtT[(c4 << 2) + 0][i] = av.x; AtT[(c4 << 2) + 1][i] = av.y;
                AtT[(c4 << 2) + 2][i] = av.z; AtT[(c4 << 2) + 3][i] = av.w;
            }
            #pragma unroll
            for (int it = 0; it < 4; ++it) {
                const int idx = tid + it * 256;
                const int r2 = idx >> 4, c = (idx & 15) << 2;
                *(float4*)&Vt[r2][c] =
                    *(const float4*)&v[(size_t)(b * SEQ + j0 + r2) * HID + h * 64 + c];
            }
        }
        __syncthreads();
        #pragma unroll
        for (int j = 0; j < 64; ++j) {
            float4 a  = *(const float4*)&AtT[j][ty << 2];
            float4 vv = *(const float4*)&Vt[j][tx << 2];
            acc[0][0] += a.x * vv.x; acc[0][1] += a.x * vv.y; acc[0][2] += a.x * vv.z; acc[0][3] += a.x * vv.w;
            acc[1][0] += a.y * vv.x; acc[1][1] += a.y * vv.y; acc[1][2] += a.y * vv.z; acc[1][3] += a.y * vv.w;
            acc[2][0] += a.z * vv.x; acc[2][1] += a.z * vv.y; acc[2][2] += a.z * vv.z; acc[2][3] += a.z * vv.w;
            acc[3][0] += a.w * vv.x; acc[3][1] += a.w * vv.y; acc[3][2] += a.w * vv.z; acc[3][3] += a.w * vv.w;
        }
    }
    #pragma unroll
    for (int i = 0; i < 4; ++i) {
        float4 o = { acc[i][0], acc[i][1], acc[i][2], acc[i][3] };
        *(float4*)&x[(size_t)(b * SEQ + i0 + (ty << 2) + i) * HID + h * 64 + (tx << 2)] = o;
    }
}

extern "C" void kernel_launch(void* const* d_in, const int* in_sizes, int n_in,
                              void* d_out, int out_size, void* d_ws, size_t ws_size,
                              hipStream_t stream) {
    (void)in_sizes; (void)n_in; (void)out_size; (void)ws_size;
    const float* query = (const float*)d_in[0];
    const float* key_  = (const float*)d_in[1];
    const float* value = (const float*)d_in[2];
    const unsigned char* mask = (const unsigned char*)d_in[3];
    const int*   pos   = (const int*)d_in[4];
    const float* Wq = (const float*)d_in[5];
    const float* bq = (const float*)d_in[6];
    const float* Wk = (const float*)d_in[7];
    const float* bk = (const float*)d_in[8];
    const float* Wv = (const float*)d_in[9];
    const float* bv = (const float*)d_in[10];
    const float* Wo = (const float*)d_in[11];
    const float* bo = (const float*)d_in[12];
    const float* rel_table = (const float*)d_in[13];

    float* out  = (float*)d_out;
    float* attn = out + (size_t)BATCH * SEQ * HID;   // 2,097,152 floats in

    // workspace layout (fp32): q | k | v | dqk | stats   (~26 MB); x aliases q.
    float* q_ws  = (float*)d_ws;
    float* k_ws  = q_ws + (size_t)BATCH * SEQ * HID;
    float* v_ws  = k_ws + (size_t)BATCH * SEQ * HID;
    float* dqk   = v_ws + (size_t)BATCH * SEQ * HID;
    float* stats = dqk + (size_t)BATCH * NHEAD * SEQ * 4;
    float* x_ws  = q_ws;  // pass 2 never reads q; safe alias

    const dim3 blk(256);
    const int M = BATCH * SEQ;  // 4096

    gemm_bias_kernel<<<dim3(M / 64, HID / 64), blk, 0, stream>>>(query, Wq, bq, q_ws, M);
    gemm_bias_kernel<<<dim3(M / 64, HID / 64), blk, 0, stream>>>(key_, Wk, bk, k_ws, M);
    gemm_bias_kernel<<<dim3(M / 64, HID / 64), blk, 0, stream>>>(value, Wv, bv, v_ws, M);
    rel_dots_kernel<<<dim3(BATCH * SEQ * NHEAD / 4), blk, 0, stream>>>(q_ws, k_ws, rel_table, dqk);
    attn_logits_kernel<<<dim3(SEQ / 64, NHEAD, BATCH), blk, 0, stream>>>(
        q_ws, k_ws, dqk, pos, mask, attn, stats);
    attn_pv_kernel<<<dim3(SEQ / 64, NHEAD, BATCH), blk, 0, stream>>>(attn, v_ws, stats, x_ws);
    gemm_bias_kernel<<<dim3(M / 64, HID / 64), blk, 0, stream>>>(x_ws, Wo, bo, out, M);
}

// Round 2
// 672.975 us; speedup vs baseline: 1.1526x; 1.1526x over previous
//
#include <hip/hip_runtime.h>
#include <math.h>

#define SEQ   2048
#define BATCH 2
#define NHEAD 8
#define HID   512
#define LG8   0.180336880f   /* log2(e)/8 : folded softmax scale */
#define MASKV -3.0e8f

typedef unsigned char  u8;
typedef unsigned short u16;
typedef short short8 __attribute__((ext_vector_type(8)));
typedef float f32x4  __attribute__((ext_vector_type(4)));

__device__ __forceinline__ u16 f2bf(float f) {
    unsigned u = __float_as_uint(f);
    u = (u + 0x7FFF + ((u >> 16) & 1)) >> 16;   // RNE
    return (u16)u;
}
__device__ __forceinline__ float bf2f(u16 h) {
    return __uint_as_float(((unsigned)h) << 16);
}

// ---------------- GEMM: C[M,512] = A[M,512] @ W[512,512] + bias (fp32) ----------------
__global__ __launch_bounds__(256) void gemm_bias_kernel(
    const float* __restrict__ A, const float* __restrict__ W,
    const float* __restrict__ bias, float* __restrict__ C, int M)
{
    __shared__ float As[16][68];
    __shared__ float Bs[16][64];
    const int tid = threadIdx.x;
    const int ty = tid >> 4, tx = tid & 15;
    const int row0 = blockIdx.x << 6;
    const int col0 = blockIdx.y << 6;
    const int am = tid >> 2, ak = (tid & 3) << 2;
    const int wk = tid >> 4, wn = (tid & 15) << 2;

    float acc[4][4] = {};
    for (int k0 = 0; k0 < HID; k0 += 16) {
        float4 a4 = *(const float4*)&A[(size_t)(row0 + am) * HID + k0 + ak];
        float4 w4 = *(const float4*)&W[(size_t)(k0 + wk) * HID + col0 + wn];
        __syncthreads();
        As[ak + 0][am] = a4.x; As[ak + 1][am] = a4.y;
        As[ak + 2][am] = a4.z; As[ak + 3][am] = a4.w;
        *(float4*)&Bs[wk][wn] = w4;
        __syncthreads();
        #pragma unroll
        for (int kk = 0; kk < 16; ++kk) {
            float4 a = *(const float4*)&As[kk][ty << 2];
            float4 w = *(const float4*)&Bs[kk][tx << 2];
            acc[0][0] += a.x * w.x; acc[0][1] += a.x * w.y; acc[0][2] += a.x * w.z; acc[0][3] += a.x * w.w;
            acc[1][0] += a.y * w.x; acc[1][1] += a.y * w.y; acc[1][2] += a.y * w.z; acc[1][3] += a.y * w.w;
            acc[2][0] += a.z * w.x; acc[2][1] += a.z * w.y; acc[2][2] += a.z * w.z; acc[2][3] += a.z * w.w;
            acc[3][0] += a.w * w.x; acc[3][1] += a.w * w.y; acc[3][2] += a.w * w.z; acc[3][3] += a.w * w.w;
        }
    }
    float4 bv = *(const float4*)&bias[col0 + (tx << 2)];
    #pragma unroll
    for (int i = 0; i < 4; ++i) {
        float4 o = { acc[i][0] + bv.x, acc[i][1] + bv.y, acc[i][2] + bv.z, acc[i][3] + bv.w };
        *(float4*)&C[(size_t)(row0 + (ty << 2) + i) * HID + col0 + (tx << 2)] = o;
    }
}

// ---------------- convert q,k -> prescaled bf16 hi/lo; v -> bf16 ----------------
__global__ __launch_bounds__(256) void convert_qkv_kernel(
    const float* __restrict__ q, const float* __restrict__ k, const float* __restrict__ v,
    u16* __restrict__ qh, u16* __restrict__ ql,
    u16* __restrict__ kh, u16* __restrict__ kl, u16* __restrict__ vb)
{
    const size_t i = ((size_t)blockIdx.x * 256 + threadIdx.x) * 4;
    float4 qv = *(const float4*)&q[i];
    float4 kv = *(const float4*)&k[i];
    float4 vv = *(const float4*)&v[i];
    ushort4 oqh, oql, okh, okl, ovb;
    float s; u16 hh;
    s = qv.x * LG8; hh = f2bf(s); oqh.x = hh; oql.x = f2bf(s - bf2f(hh));
    s = qv.y * LG8; hh = f2bf(s); oqh.y = hh; oql.y = f2bf(s - bf2f(hh));
    s = qv.z * LG8; hh = f2bf(s); oqh.z = hh; oql.z = f2bf(s - bf2f(hh));
    s = qv.w * LG8; hh = f2bf(s); oqh.w = hh; oql.w = f2bf(s - bf2f(hh));
    s = kv.x;       hh = f2bf(s); okh.x = hh; okl.x = f2bf(s - bf2f(hh));
    s = kv.y;       hh = f2bf(s); okh.y = hh; okl.y = f2bf(s - bf2f(hh));
    s = kv.z;       hh = f2bf(s); okh.z = hh; okl.z = f2bf(s - bf2f(hh));
    s = kv.w;       hh = f2bf(s); okh.w = hh; okl.w = f2bf(s - bf2f(hh));
    ovb.x = f2bf(vv.x); ovb.y = f2bf(vv.y); ovb.z = f2bf(vv.z); ovb.w = f2bf(vv.w);
    *(ushort4*)&qh[i] = oqh; *(ushort4*)&ql[i] = oql;
    *(ushort4*)&kh[i] = okh; *(ushort4*)&kl[i] = okl;
    *(ushort4*)&vb[i] = ovb;
}

// ---------------- fused pos/mask byte table: pm = mask ? 3 : pos ----------------
__global__ __launch_bounds__(256) void convert_pm_kernel(
    const int* __restrict__ pos, const u8* __restrict__ mask, u8* __restrict__ pm)
{
    const size_t s = ((size_t)blockIdx.x * 256 + threadIdx.x) * 4;
    int4  p = *(const int4*)&pos[s & (size_t)(SEQ * SEQ - 1)];
    uchar4 m = *(const uchar4*)&mask[s];
    uchar4 o;
    o.x = m.x ? (u8)3 : (u8)p.x;
    o.y = m.y ? (u8)3 : (u8)p.y;
    o.z = m.z ? (u8)3 : (u8)p.z;
    o.w = m.w ? (u8)3 : (u8)p.w;
    *(uchar4*)&pm[s] = o;
}

// ---------------- rel dots: dqk[bh,i,r] = LG8 * sum_d (q+k)[b,i,h,d] * rel_table[r,d] ----------------
__global__ __launch_bounds__(256) void rel_dots_kernel(
    const float* __restrict__ q, const float* __restrict__ k,
    const float* __restrict__ rel_table, float* __restrict__ dqk)
{
    const int w = blockIdx.x * 4 + (threadIdx.x >> 6);
    const int lane = threadIdx.x & 63;
    const int h = w % NHEAD;
    const int is = w / NHEAD;            // b*SEQ + i
    const int b = is / SEQ;
    const int i = is % SEQ;
    const size_t base = (size_t)is * HID + h * 64 + lane;
    const float s = q[base] + k[base];
    float p0 = s * rel_table[lane];
    float p1 = s * rel_table[64 + lane];
    float p2 = s * rel_table[128 + lane];
    #pragma unroll
    for (int off = 32; off; off >>= 1) {
        p0 += __shfl_xor(p0, off);
        p1 += __shfl_xor(p1, off);
        p2 += __shfl_xor(p2, off);
    }
    if (lane == 0) {
        size_t o = (((size_t)b * NHEAD + h) * SEQ + i) << 2;
        dqk[o + 0] = p0 * LG8; dqk[o + 1] = p1 * LG8; dqk[o + 2] = p2 * LG8;
    }
}

// ---------------- pass 1: per-row denominator (no logits write) ----------------
// block = (i-tile 64, h, b), 4 waves; wave w owns rows w*16..w*16+15 (MFMA M).
__global__ __launch_bounds__(256) void attn_stats_kernel(
    const u16* __restrict__ qh, const u16* __restrict__ ql,
    const u16* __restrict__ kh, const u16* __restrict__ kl,
    const float* __restrict__ dqk, const u8* __restrict__ pm,
    float* __restrict__ invl)
{
    __shared__ __align__(16) u16 Kh[64 * 72];
    __shared__ __align__(16) u16 Kl[64 * 72];
    __shared__ __align__(16) u8  PM[64 * 64];
    __shared__ float Ds[64][4];
    const int tid = threadIdx.x;
    const int wave = tid >> 6, lane = tid & 63;
    const int quad = lane >> 4, l15 = lane & 15;
    const int b = blockIdx.z, h = blockIdx.y, i0 = blockIdx.x << 6;
    const size_t bh = (size_t)(b * NHEAD + h);

    {
        const int i = tid >> 2, r = tid & 3;
        Ds[i][r] = (r == 3) ? MASKV : dqk[((bh * SEQ + i0 + i) << 2) + r];
    }
    const int irow = (wave << 4) + l15;
    const size_t qbase = ((size_t)(b * SEQ + i0 + irow)) * HID + h * 64 + (quad << 3);
    const short8 aqh0 = *(const short8*)&qh[qbase];
    const short8 aqh1 = *(const short8*)&qh[qbase + 32];
    const short8 aql0 = *(const short8*)&ql[qbase];
    const short8 aql1 = *(const short8*)&ql[qbase + 32];

    float srow[4] = {0.f, 0.f, 0.f, 0.f};

    for (int jt = 0; jt < SEQ / 64; ++jt) {
        const int j0 = jt << 6;
        __syncthreads();
        {
            const int rr = tid >> 3, cc = (tid & 7) << 3;
            const size_t g = ((size_t)(b * SEQ + j0 + rr)) * HID + h * 64 + cc;
            *(short8*)&Kh[rr * 72 + cc] = *(const short8*)&kh[g];
            *(short8*)&Kl[rr * 72 + cc] = *(const short8*)&kl[g];
            const size_t g2 = g + (size_t)32 * HID;
            *(short8*)&Kh[(rr + 32) * 72 + cc] = *(const short8*)&kh[g2];
            *(short8*)&Kl[(rr + 32) * 72 + cc] = *(const short8*)&kl[g2];
        }
        {
            const int r = tid >> 2, c = (tid & 3) << 4;
            *(uint4*)&PM[r * 64 + c] =
                *(const uint4*)&pm[((size_t)b * SEQ + i0 + r) * SEQ + j0 + c];
        }
        __syncthreads();

        #pragma unroll
        for (int sub = 0; sub < 4; ++sub) {
            const int n = (sub << 4) + l15;
            const short8 bh0 = *(const short8*)&Kh[n * 72 + (quad << 3)];
            const short8 bh1 = *(const short8*)&Kh[n * 72 + 32 + (quad << 3)];
            const short8 bl0 = *(const short8*)&Kl[n * 72 + (quad << 3)];
            const short8 bl1 = *(const short8*)&Kl[n * 72 + 32 + (quad << 3)];
            f32x4 acc = {0.f, 0.f, 0.f, 0.f};
            acc = __builtin_amdgcn_mfma_f32_16x16x32_bf16(aqh0, bh0, acc, 0, 0, 0);
            acc = __builtin_amdgcn_mfma_f32_16x16x32_bf16(aqh1, bh1, acc, 0, 0, 0);
            acc = __builtin_amdgcn_mfma_f32_16x16x32_bf16(aql0, bh0, acc, 0, 0, 0);
            acc = __builtin_amdgcn_mfma_f32_16x16x32_bf16(aql1, bh1, acc, 0, 0, 0);
            acc = __builtin_amdgcn_mfma_f32_16x16x32_bf16(aqh0, bl0, acc, 0, 0, 0);
            acc = __builtin_amdgcn_mfma_f32_16x16x32_bf16(aqh1, bl1, acc, 0, 0, 0);
            #pragma unroll
            for (int r = 0; r < 4; ++r) {
                const int il = (wave << 4) + (quad << 2) + r;
                const u8 p = PM[il * 64 + (sub << 4) + l15];
                srow[r] += exp2f(acc[r] + Ds[il][p]);
            }
        }
    }
    #pragma unroll
    for (int r = 0; r < 4; ++r) {
        float s = srow[r];
        s += __shfl_xor(s, 1); s += __shfl_xor(s, 2);
        s += __shfl_xor(s, 4); s += __shfl_xor(s, 8);
        if (l15 == 0)
            invl[bh * SEQ + i0 + (wave << 4) + (quad << 2) + r] = 1.0f / s;
    }
}

// ---------------- pass 2: recompute logits, write attn once, fused PV ----------------
__global__ __launch_bounds__(256) void attn_fused_kernel(
    const u16* __restrict__ qh, const u16* __restrict__ ql,
    const u16* __restrict__ kh, const u16* __restrict__ kl,
    const u16* __restrict__ vb, const float* __restrict__ dqk,
    const u8* __restrict__ pm, const float* __restrict__ invl,
    float* __restrict__ attn, float* __restrict__ x)
{
    __shared__ __align__(16) u16 Kh[64 * 72];
    __shared__ __align__(16) u16 Kl[64 * 72];
    __shared__ __align__(16) u16 VtT[64 * 72];
    __shared__ __align__(16) u16 Pst[4][16 * 72];
    __shared__ __align__(16) u8  PM[64 * 64];
    __shared__ float Ds[64][4];
    const int tid = threadIdx.x;
    const int wave = tid >> 6, lane = tid & 63;
    const int quad = lane >> 4, l15 = lane & 15;
    const int b = blockIdx.z, h = blockIdx.y, i0 = blockIdx.x << 6;
    const size_t bh = (size_t)(b * NHEAD + h);

    {
        const int i = tid >> 2, r = tid & 3;
        Ds[i][r] = (r == 3) ? MASKV : dqk[((bh * SEQ + i0 + i) << 2) + r];
    }
    float inv_r[4];
    #pragma unroll
    for (int r = 0; r < 4; ++r)
        inv_r[r] = invl[bh * SEQ + i0 + (wave << 4) + (quad << 2) + r];

    const int irow = (wave << 4) + l15;
    const size_t qbase = ((size_t)(b * SEQ + i0 + irow)) * HID + h * 64 + (quad << 3);
    const short8 aqh0 = *(const short8*)&qh[qbase];
    const short8 aqh1 = *(const short8*)&qh[qbase + 32];
    const short8 aql0 = *(const short8*)&ql[qbase];
    const short8 aql1 = *(const short8*)&ql[qbase + 32];

    f32x4 accX[4] = {{0.f,0.f,0.f,0.f},{0.f,0.f,0.f,0.f},{0.f,0.f,0.f,0.f},{0.f,0.f,0.f,0.f}};

    for (int jt = 0; jt < SEQ / 64; ++jt) {
        const int j0 = jt << 6;
        __syncthreads();
        {
            const int rr = tid >> 3, cc = (tid & 7) << 3;
            const size_t g = ((size_t)(b * SEQ + j0 + rr)) * HID + h * 64 + cc;
            *(short8*)&Kh[rr * 72 + cc] = *(const short8*)&kh[g];
            *(short8*)&Kl[rr * 72 + cc] = *(const short8*)&kl[g];
            const size_t g2 = g + (size_t)32 * HID;
            *(short8*)&Kh[(rr + 32) * 72 + cc] = *(const short8*)&kh[g2];
            *(short8*)&Kl[(rr + 32) * 72 + cc] = *(const short8*)&kl[g2];
        }
        {
            const int r = tid >> 2, c = (tid & 3) << 4;
            *(uint4*)&PM[r * 64 + c] =
                *(const uint4*)&pm[((size_t)b * SEQ + i0 + r) * SEQ + j0 + c];
        }
        {   // stage V^T tile (d-major) for PV A-operand
            const int jr = tid & 63, d0 = (tid >> 6) << 4;
            const size_t g = ((size_t)(b * SEQ + j0 + jr)) * HID + h * 64 + d0;
            const short8 v0 = *(const short8*)&vb[g];
            const short8 v1 = *(const short8*)&vb[g + 8];
            #pragma unroll
            for (int e = 0; e < 8; ++e) {
                VtT[(d0 + e) * 72 + jr]     = (u16)v0[e];
                VtT[(d0 + 8 + e) * 72 + jr] = (u16)v1[e];
            }
        }
        __syncthreads();

        #pragma unroll
        for (int sub = 0; sub < 4; ++sub) {
            const int n = (sub << 4) + l15;
            const short8 bh0 = *(const short8*)&Kh[n * 72 + (quad << 3)];
            const short8 bh1 = *(const short8*)&Kh[n * 72 + 32 + (quad << 3)];
            const short8 bl0 = *(const short8*)&Kl[n * 72 + (quad << 3)];
            const short8 bl1 = *(const short8*)&Kl[n * 72 + 32 + (quad << 3)];
            f32x4 acc = {0.f, 0.f, 0.f, 0.f};
            acc = __builtin_amdgcn_mfma_f32_16x16x32_bf16(aqh0, bh0, acc, 0, 0, 0);
            acc = __builtin_amdgcn_mfma_f32_16x16x32_bf16(aqh1, bh1, acc, 0, 0, 0);
            acc = __builtin_amdgcn_mfma_f32_16x16x32_bf16(aql0, bh0, acc, 0, 0, 0);
            acc = __builtin_amdgcn_mfma_f32_16x16x32_bf16(aql1, bh1, acc, 0, 0, 0);
            acc = __builtin_amdgcn_mfma_f32_16x16x32_bf16(aqh0, bl0, acc, 0, 0, 0);
            acc = __builtin_amdgcn_mfma_f32_16x16x32_bf16(aqh1, bl1, acc, 0, 0, 0);
            #pragma unroll
            for (int r = 0; r < 4; ++r) {
                const int il = (wave << 4) + (quad << 2) + r;
                const u8 p = PM[il * 64 + (sub << 4) + l15];
                const float pr = exp2f(acc[r] + Ds[il][p]) * inv_r[r];
                attn[(bh * SEQ + i0 + il) * SEQ + j0 + (sub << 4) + l15] = pr;
                Pst[wave][((quad << 2) + r) * 72 + (sub << 4) + l15] = f2bf(pr);
            }
        }
        // PV: X^T = V^T @ P^T  (wave-private P strip; same-wave LDS ordering)
        const short8 bp0 = *(const short8*)&Pst[wave][l15 * 72 + (quad << 3)];
        const short8 bp1 = *(const short8*)&Pst[wave][l15 * 72 + 32 + (quad << 3)];
        #pragma unroll
        for (int m = 0; m < 4; ++m) {
            const short8 av0 = *(const short8*)&VtT[((m << 4) + l15) * 72 + (quad << 3)];
            const short8 av1 = *(const short8*)&VtT[((m << 4) + l15) * 72 + 32 + (quad << 3)];
            accX[m] = __builtin_amdgcn_mfma_f32_16x16x32_bf16(av0, bp0, accX[m], 0, 0, 0);
            accX[m] = __builtin_amdgcn_mfma_f32_16x16x32_bf16(av1, bp1, accX[m], 0, 0, 0);
        }
    }
    const size_t xrow = ((size_t)(b * SEQ + i0 + (wave << 4) + l15)) * HID + h * 64;
    #pragma unroll
    for (int m = 0; m < 4; ++m) {
        *(f32x4*)&x[xrow + (m << 4) + (quad << 2)] = accX[m];
    }
}

extern "C" void kernel_launch(void* const* d_in, const int* in_sizes, int n_in,
                              void* d_out, int out_size, void* d_ws, size_t ws_size,
                              hipStream_t stream) {
    (void)in_sizes; (void)n_in; (void)out_size; (void)ws_size;
    const float* query = (const float*)d_in[0];
    const float* key_  = (const float*)d_in[1];
    const float* value = (const float*)d_in[2];
    const u8*    mask  = (const u8*)d_in[3];
    const int*   pos   = (const int*)d_in[4];
    const float* Wq = (const float*)d_in[5];
    const float* bq = (const float*)d_in[6];
    const float* Wk = (const float*)d_in[7];
    const float* bk = (const float*)d_in[8];
    const float* Wv = (const float*)d_in[9];
    const float* bv = (const float*)d_in[10];
    const float* Wo = (const float*)d_in[11];
    const float* bo = (const float*)d_in[12];
    const float* rel_table = (const float*)d_in[13];

    float* out  = (float*)d_out;
    float* attn = out + (size_t)BATCH * SEQ * HID;

    // ws layout: q|k|v fp32 (8MB ea) | dqk | invl | qh|ql|kh|kl|vb bf16 (4MB ea) | pm (8MB)  ~53MB
    float* q_ws = (float*)d_ws;
    float* k_ws = q_ws + (size_t)2097152;
    float* v_ws = k_ws + (size_t)2097152;
    float* dqk  = v_ws + (size_t)2097152;
    float* invl = dqk + (size_t)131072;
    u16* qh = (u16*)(invl + 32768);
    u16* ql = qh + (size_t)2097152;
    u16* kh = ql + (size_t)2097152;
    u16* kl = kh + (size_t)2097152;
    u16* vb = kl + (size_t)2097152;
    u8*  pm = (u8*)(vb + (size_t)2097152);
    float* x_ws = q_ws;   // fused kernel reads qh/ql only; q_ws free by then

    const dim3 blk(256);
    const int M = BATCH * SEQ;

    gemm_bias_kernel<<<dim3(M / 64, HID / 64), blk, 0, stream>>>(query, Wq, bq, q_ws, M);
    gemm_bias_kernel<<<dim3(M / 64, HID / 64), blk, 0, stream>>>(key_, Wk, bk, k_ws, M);
    gemm_bias_kernel<<<dim3(M / 64, HID / 64), blk, 0, stream>>>(value, Wv, bv, v_ws, M);
    rel_dots_kernel<<<dim3(BATCH * SEQ * NHEAD / 4), blk, 0, stream>>>(q_ws, k_ws, rel_table, dqk);
    convert_qkv_kernel<<<dim3(2048), blk, 0, stream>>>(q_ws, k_ws, v_ws, qh, ql, kh, kl, vb);
    convert_pm_kernel<<<dim3(8192), blk, 0, stream>>>(pos, mask, pm);
    attn_stats_kernel<<<dim3(SEQ / 64, NHEAD, BATCH), blk, 0, stream>>>(
        qh, ql, kh, kl, dqk, pm, invl);
    attn_fused_kernel<<<dim3(SEQ / 64, NHEAD, BATCH), blk, 0, stream>>>(
        qh, ql, kh, kl, vb, dqk, pm, invl, attn, x_ws);
    gemm_bias_kernel<<<dim3(M / 64, HID / 64), blk, 0, stream>>>(x_ws, Wo, bo, out, M);
}